// Round 3
// baseline (369.858 us; speedup 1.0000x reference)
//
#include <hip/hip_runtime.h>
#include <math.h>

// Problem constants (from reference)
#define PN 32
#define PM 100
#define PK 500
#define PE 50

static constexpr float DEG2RAD = 0.017453292519943295f; // pi/180
static constexpr float TWO_R   = 2.0f * 6371.0f;

// Native 2-float vector (clang ext_vector) — required by
// __builtin_nontemporal_store (HIP's float2 class type is rejected).
typedef float f32x2 __attribute__((ext_vector_type(2)));

// out[n,m,k,e] = C[n,m,e] + ds[n,m,k] * D[n,m,e]
//   C[e] = esl[i][e] + (etl[i][e]*(500-dt) + etu[i][e]*dt) / 500
//   D[e] = (esu[i][e] - esl[i][e]) / 1000
//   i = (m < traj_len[n]) ? 1 : 0, dt = vec[n,m]
//   ds = 2*R*asin(sqrt(clip(hav,0,1)))
//
// Round-1 structure (register-resident C/D, fixed e-pair per thread,
// broadcast LDS read of ds, coalesced 8B stores) PLUS nontemporal
// stores. Theory: output stores run at ~2.5 TB/s because store-miss
// write-allocate (RFO) doubles HBM traffic (320 MB writes + ~320 MB
// hidden reads). `nt` stores bypass L2 allocation, like the rocclr
// fill path (5.87 TB/s with ~0 FETCH_SIZE).
__global__ __launch_bounds__(256) void embed_kernel(
    const int*   __restrict__ traj_loc,  // N*M
    const float* __restrict__ poi,       // LOC*2
    const float* __restrict__ vec,       // N*M
    const int*   __restrict__ traj_len,  // N
    const int*   __restrict__ cand,      // N*K
    const float* __restrict__ emb_su,    // 2*E
    const float* __restrict__ emb_sl,    // 2*E
    const float* __restrict__ emb_tu,    // 2*E
    const float* __restrict__ emb_tl,    // 2*E
    float*       __restrict__ out)       // N*M*K*E
{
    const int nm  = blockIdx.x;        // 0 .. N*M-1
    const int n   = nm / PM;
    const int m   = nm - n * PM;
    const int tid = threadIdx.x;

    __shared__ float s_ds[PK];

    // --- per-(n,m) uniform values (scalar loads: addresses tid-independent)
    const int   tl   = traj_loc[nm];
    const float lat1 = poi[2 * tl]     * DEG2RAD;
    const float lon1 = poi[2 * tl + 1] * DEG2RAD;
    const float coslat1 = __cosf(lat1);

    // --- stage ds[k]: haversine distance traj(n,m) -> cand(n,k)
    for (int k = tid; k < PK; k += 256) {
        const int   cl   = cand[n * PK + k];
        const float lat2 = poi[2 * cl]     * DEG2RAD;
        const float lon2 = poi[2 * cl + 1] * DEG2RAD;
        const float sdlat = __sinf(0.5f * (lat2 - lat1));
        const float sdlon = __sinf(0.5f * (lon2 - lon1));
        float a = sdlat * sdlat + coslat1 * __cosf(lat2) * (sdlon * sdlon);
        a = fminf(fmaxf(a, 0.0f), 1.0f);
        s_ds[k] = TWO_R * asinf(sqrtf(a));
    }

    __syncthreads();

    if (tid >= 250) return;           // 250 threads cover 10 rows x 25 pairs

    const int p  = tid % 25;          // e-pair index: e = {2p, 2p+1}, FIXED
    const int k0 = tid / 25;          // starting row 0..9, k strides by 10

    const int   i  = (m < traj_len[n]) ? 1 : 0;
    const float dt = vec[nm];

    // emb tables are 2x50 floats, L1-hot; 8B loads are aligned (e even)
    const f32x2 esl = reinterpret_cast<const f32x2*>(emb_sl)[i * 25 + p];
    const f32x2 esu = reinterpret_cast<const f32x2*>(emb_su)[i * 25 + p];
    const f32x2 etl = reinterpret_cast<const f32x2*>(emb_tl)[i * 25 + p];
    const f32x2 etu = reinterpret_cast<const f32x2*>(emb_tu)[i * 25 + p];

    const float C0 = esl.x + (etl.x * (500.0f - dt) + etu.x * dt) * (1.0f / 500.0f);
    const float C1 = esl.y + (etl.y * (500.0f - dt) + etu.y * dt) * (1.0f / 500.0f);
    const float D0 = (esu.x - esl.x) * (1.0f / 1000.0f);
    const float D1 = (esu.y - esl.y) * (1.0f / 1000.0f);

    // f32x2 index within this (n,m) tile: k*25 + p; per-iteration stride
    // is 10 rows = 250 f32x2 = 2000 B (stays perfectly coalesced).
    f32x2* __restrict__ out2 =
        reinterpret_cast<f32x2*>(out + (size_t)nm * (PK * PE)) + (k0 * 25 + p);

    #pragma unroll 10
    for (int it = 0; it < 50; ++it) {
        const float ds = s_ds[k0 + it * 10];   // 25 lanes share addr -> broadcast
        f32x2 v;
        v.x = fmaf(ds, D0, C0);
        v.y = fmaf(ds, D1, C1);
        __builtin_nontemporal_store(v, &out2[it * 250]);  // bypass L2 alloc (no RFO)
    }
}

extern "C" void kernel_launch(void* const* d_in, const int* in_sizes, int n_in,
                              void* d_out, int out_size, void* d_ws, size_t ws_size,
                              hipStream_t stream) {
    const int*   traj_loc = (const int*)  d_in[0];
    const float* poi      = (const float*)d_in[1];
    const float* vec      = (const float*)d_in[2];
    const int*   traj_len = (const int*)  d_in[3];
    const int*   cand     = (const int*)  d_in[4];
    const float* emb_su   = (const float*)d_in[5];
    const float* emb_sl   = (const float*)d_in[6];
    const float* emb_tu   = (const float*)d_in[7];
    const float* emb_tl   = (const float*)d_in[8];
    float* out = (float*)d_out;

    dim3 grid(PN * PM);   // 3200 blocks, one per (n,m)
    dim3 block(256);
    embed_kernel<<<grid, block, 0, stream>>>(
        traj_loc, poi, vec, traj_len, cand,
        emb_su, emb_sl, emb_tu, emb_tl, out);
}

// Round 4
// 368.807 us; speedup vs baseline: 1.0028x; 1.0028x over previous
//
#include <hip/hip_runtime.h>
#include <math.h>

// Problem constants (from reference)
#define PN 32
#define PM 100
#define PK 500
#define PE 50
#define NM (PN * PM)                    // 3200
#define TOT2 (NM * PK * (PE / 2))       // 40,000,000 f32x2 output pairs

static constexpr float DEG2RAD = 0.017453292519943295f; // pi/180
static constexpr float TWO_R   = 2.0f * 6371.0f;

typedef float f32x2 __attribute__((ext_vector_type(2)));

// ---------------------------------------------------------------------------
// Kernel A: per (n,m), precompute ds[500] and C2/D2[25] into workspace.
// No LDS, no barrier. ~7.7 MB total, LLC-resident.
//   ws_ds[nm*500 + k]  = 2*R*asin(sqrt(clip(hav,0,1)))
//   ws_c [nm*25 + p]   = C[2p], C[2p+1]   (C = esl + (etl*(500-dt)+etu*dt)/500)
//   ws_d [nm*25 + p]   = D[2p], D[2p+1]   (D = (esu-esl)/1000)
// ---------------------------------------------------------------------------
__global__ __launch_bounds__(256) void precompute_kernel(
    const int*   __restrict__ traj_loc,  // N*M
    const float* __restrict__ poi,       // LOC*2
    const float* __restrict__ vec,       // N*M
    const int*   __restrict__ traj_len,  // N
    const int*   __restrict__ cand,      // N*K
    const float* __restrict__ emb_su,    // 2*E
    const float* __restrict__ emb_sl,    // 2*E
    const float* __restrict__ emb_tu,    // 2*E
    const float* __restrict__ emb_tl,    // 2*E
    float*       __restrict__ ws_ds,     // NM*PK
    f32x2*       __restrict__ ws_c,      // NM*25
    f32x2*       __restrict__ ws_d)      // NM*25
{
    const int nm  = blockIdx.x;
    const int n   = nm / PM;
    const int m   = nm - n * PM;
    const int tid = threadIdx.x;

    const int   tl   = traj_loc[nm];
    const float lat1 = poi[2 * tl]     * DEG2RAD;
    const float lon1 = poi[2 * tl + 1] * DEG2RAD;
    const float coslat1 = __cosf(lat1);

    for (int k = tid; k < PK; k += 256) {
        const int   cl   = cand[n * PK + k];
        const float lat2 = poi[2 * cl]     * DEG2RAD;
        const float lon2 = poi[2 * cl + 1] * DEG2RAD;
        const float sdlat = __sinf(0.5f * (lat2 - lat1));
        const float sdlon = __sinf(0.5f * (lon2 - lon1));
        float a = sdlat * sdlat + coslat1 * __cosf(lat2) * (sdlon * sdlon);
        a = fminf(fmaxf(a, 0.0f), 1.0f);
        ws_ds[nm * PK + k] = TWO_R * asinf(sqrtf(a));
    }

    if (tid < 25) {
        const int   i  = (m < traj_len[n]) ? 1 : 0;
        const float dt = vec[nm];
        const f32x2 esl = reinterpret_cast<const f32x2*>(emb_sl)[i * 25 + tid];
        const f32x2 esu = reinterpret_cast<const f32x2*>(emb_su)[i * 25 + tid];
        const f32x2 etl = reinterpret_cast<const f32x2*>(emb_tl)[i * 25 + tid];
        const f32x2 etu = reinterpret_cast<const f32x2*>(emb_tu)[i * 25 + tid];
        f32x2 C, D;
        C.x = esl.x + (etl.x * (500.0f - dt) + etu.x * dt) * (1.0f / 500.0f);
        C.y = esl.y + (etl.y * (500.0f - dt) + etu.y * dt) * (1.0f / 500.0f);
        D.x = (esu.x - esl.x) * (1.0f / 1000.0f);
        D.y = (esu.y - esl.y) * (1.0f / 1000.0f);
        ws_c[nm * 25 + tid] = C;
        ws_d[nm * 25 + tid] = D;
    }
}

// ---------------------------------------------------------------------------
// Kernel B: fill-shaped grid-stride streamer. Per 8B output pair:
// 3 L1/L2-hot loads (ds scalar broadcast across 25 lanes, C2, D2),
// 2 fmaf, 1 coalesced 8B store. No LDS, no barrier, no block tail.
// Linear pair index i = nm*12500 + k*25 + p matches output layout exactly.
// ---------------------------------------------------------------------------
__global__ __launch_bounds__(256) void stream_kernel(
    const float* __restrict__ ws_ds,
    const f32x2* __restrict__ ws_c,
    const f32x2* __restrict__ ws_d,
    f32x2*       __restrict__ out2)
{
    const unsigned stride = gridDim.x * 256u;
    for (unsigned i = blockIdx.x * 256u + threadIdx.x; i < (unsigned)TOT2;
         i += stride) {
        const unsigned nm = i / 12500u;          // magic-mul
        const unsigned r  = i - nm * 12500u;
        const unsigned k  = r / 25u;             // magic-mul
        const unsigned p  = r - k * 25u;
        const float ds = ws_ds[nm * PK + k];
        const f32x2 c  = ws_c[nm * 25 + p];
        const f32x2 d  = ws_d[nm * 25 + p];
        f32x2 v;
        v.x = fmaf(ds, d.x, c.x);
        v.y = fmaf(ds, d.y, c.y);
        out2[i] = v;
    }
}

// ---------------------------------------------------------------------------
// Fallback (ws too small): round-1 single-kernel path (LDS stage + stream).
// ---------------------------------------------------------------------------
__global__ __launch_bounds__(256) void embed_kernel(
    const int*   __restrict__ traj_loc,
    const float* __restrict__ poi,
    const float* __restrict__ vec,
    const int*   __restrict__ traj_len,
    const int*   __restrict__ cand,
    const float* __restrict__ emb_su,
    const float* __restrict__ emb_sl,
    const float* __restrict__ emb_tu,
    const float* __restrict__ emb_tl,
    float*       __restrict__ out)
{
    const int nm  = blockIdx.x;
    const int n   = nm / PM;
    const int m   = nm - n * PM;
    const int tid = threadIdx.x;

    __shared__ float s_ds[PK];

    const int   tl   = traj_loc[nm];
    const float lat1 = poi[2 * tl]     * DEG2RAD;
    const float lon1 = poi[2 * tl + 1] * DEG2RAD;
    const float coslat1 = __cosf(lat1);

    for (int k = tid; k < PK; k += 256) {
        const int   cl   = cand[n * PK + k];
        const float lat2 = poi[2 * cl]     * DEG2RAD;
        const float lon2 = poi[2 * cl + 1] * DEG2RAD;
        const float sdlat = __sinf(0.5f * (lat2 - lat1));
        const float sdlon = __sinf(0.5f * (lon2 - lon1));
        float a = sdlat * sdlat + coslat1 * __cosf(lat2) * (sdlon * sdlon);
        a = fminf(fmaxf(a, 0.0f), 1.0f);
        s_ds[k] = TWO_R * asinf(sqrtf(a));
    }

    __syncthreads();

    if (tid >= 250) return;

    const int p  = tid % 25;
    const int k0 = tid / 25;

    const int   i  = (m < traj_len[n]) ? 1 : 0;
    const float dt = vec[nm];

    const f32x2 esl = reinterpret_cast<const f32x2*>(emb_sl)[i * 25 + p];
    const f32x2 esu = reinterpret_cast<const f32x2*>(emb_su)[i * 25 + p];
    const f32x2 etl = reinterpret_cast<const f32x2*>(emb_tl)[i * 25 + p];
    const f32x2 etu = reinterpret_cast<const f32x2*>(emb_tu)[i * 25 + p];

    const float C0 = esl.x + (etl.x * (500.0f - dt) + etu.x * dt) * (1.0f / 500.0f);
    const float C1 = esl.y + (etl.y * (500.0f - dt) + etu.y * dt) * (1.0f / 500.0f);
    const float D0 = (esu.x - esl.x) * (1.0f / 1000.0f);
    const float D1 = (esu.y - esl.y) * (1.0f / 1000.0f);

    f32x2* __restrict__ out2 =
        reinterpret_cast<f32x2*>(out + (size_t)nm * (PK * PE)) + (k0 * 25 + p);

    #pragma unroll 10
    for (int it = 0; it < 50; ++it) {
        const float ds = s_ds[k0 + it * 10];
        f32x2 v;
        v.x = fmaf(ds, D0, C0);
        v.y = fmaf(ds, D1, C1);
        out2[it * 250] = v;
    }
}

extern "C" void kernel_launch(void* const* d_in, const int* in_sizes, int n_in,
                              void* d_out, int out_size, void* d_ws, size_t ws_size,
                              hipStream_t stream) {
    const int*   traj_loc = (const int*)  d_in[0];
    const float* poi      = (const float*)d_in[1];
    const float* vec      = (const float*)d_in[2];
    const int*   traj_len = (const int*)  d_in[3];
    const int*   cand     = (const int*)  d_in[4];
    const float* emb_su   = (const float*)d_in[5];
    const float* emb_sl   = (const float*)d_in[6];
    const float* emb_tu   = (const float*)d_in[7];
    const float* emb_tl   = (const float*)d_in[8];
    float* out = (float*)d_out;

    // Workspace layout: ds[NM*PK] floats (6.40 MB), then C2[NM*25] f32x2
    // (0.64 MB), then D2[NM*25] f32x2 (0.64 MB). Total 7.68 MB.
    const size_t ds_bytes = (size_t)NM * PK * sizeof(float);
    const size_t cd_bytes = (size_t)NM * 25 * sizeof(f32x2);
    const size_t need     = ds_bytes + 2 * cd_bytes;

    if (d_ws != nullptr && ws_size >= need) {
        float* ws_ds = (float*)d_ws;
        f32x2* ws_c  = (f32x2*)((char*)d_ws + ds_bytes);
        f32x2* ws_d  = (f32x2*)((char*)d_ws + ds_bytes + cd_bytes);

        precompute_kernel<<<dim3(NM), dim3(256), 0, stream>>>(
            traj_loc, poi, vec, traj_len, cand,
            emb_su, emb_sl, emb_tu, emb_tl,
            ws_ds, ws_c, ws_d);

        stream_kernel<<<dim3(4096), dim3(256), 0, stream>>>(
            ws_ds, ws_c, ws_d, reinterpret_cast<f32x2*>(out));
    } else {
        embed_kernel<<<dim3(NM), dim3(256), 0, stream>>>(
            traj_loc, poi, vec, traj_len, cand,
            emb_su, emb_sl, emb_tu, emb_tl, out);
    }
}

// Round 5
// 350.342 us; speedup vs baseline: 1.0557x; 1.0527x over previous
//
#include <hip/hip_runtime.h>
#include <math.h>

// Problem constants (from reference)
#define PN 32
#define PM 100
#define PK 500
#define PE 50

static constexpr float DEG2RAD = 0.017453292519943295f; // pi/180
static constexpr float TWO_R   = 2.0f * 6371.0f;

// Native 4-float vector (clang ext_vector) — required by
// __builtin_nontemporal_store (HIP's float4 class type is rejected).
typedef float f32x4 __attribute__((ext_vector_type(4)));

// out[n,m,k,e] = C[n,m,e] + ds[n,m,k] * D[n,m,e]
//   C[e] = esl[i][e] + (etl[i][e]*(500-dt) + etu[i][e]*dt) / 500
//   D[e] = (esu[i][e] - esl[i][e]) / 1000
//   i = (m < traj_len[n]) ? 1 : 0, dt = vec[n,m]
//   ds = 2*R*asin(sqrt(clip(hav,0,1)))
//
// Round-0 structure (measured ~129 us kernel: LDS-staged ds/C/D, linear
// float4 sweep with wrap branches — wrap cost proven free vs R1) with ONE
// change: the 16B store is NONTEMPORAL. Theory: the 6 TB/s rocclr fill
// writes nt dwordx4 (FETCH~0 on 1.28GB); our nt attempt at 8B width
// regressed (R3) plausibly because L2-bypassed 8B granules straddle the
// 32B HBM burst, while 16B nt granules pair-merge — the fill's exact shape.
__global__ __launch_bounds__(256) void embed_kernel(
    const int*   __restrict__ traj_loc,  // N*M
    const float* __restrict__ poi,       // LOC*2
    const float* __restrict__ vec,       // N*M
    const int*   __restrict__ traj_len,  // N
    const int*   __restrict__ cand,      // N*K
    const float* __restrict__ emb_su,    // 2*E
    const float* __restrict__ emb_sl,    // 2*E
    const float* __restrict__ emb_tu,    // 2*E
    const float* __restrict__ emb_tl,    // 2*E
    float*       __restrict__ out)       // N*M*K*E
{
    const int nm  = blockIdx.x;        // 0 .. N*M-1
    const int n   = nm / PM;
    const int m   = nm - n * PM;
    const int tid = threadIdx.x;

    __shared__ float s_ds[PK];
    __shared__ float s_C[PE];
    __shared__ float s_D[PE];

    // --- per-(n,m) uniform values (scalar loads: addresses tid-independent)
    const int   tl   = traj_loc[nm];
    const float lat1 = poi[2 * tl]     * DEG2RAD;
    const float lon1 = poi[2 * tl + 1] * DEG2RAD;
    const float coslat1 = __cosf(lat1);

    // --- stage C[e], D[e]
    if (tid < PE) {
        const int   i  = (m < traj_len[n]) ? 1 : 0;
        const float dt = vec[nm];
        const float esl = emb_sl[i * PE + tid];
        const float esu = emb_su[i * PE + tid];
        const float etl = emb_tl[i * PE + tid];
        const float etu = emb_tu[i * PE + tid];
        s_C[tid] = esl + (etl * (500.0f - dt) + etu * dt) * (1.0f / 500.0f);
        s_D[tid] = (esu - esl) * (1.0f / 1000.0f);
    }

    // --- stage ds[k]: haversine distance traj(n,m) -> cand(n,k)
    for (int k = tid; k < PK; k += 256) {
        const int   cl   = cand[n * PK + k];
        const float lat2 = poi[2 * cl]     * DEG2RAD;
        const float lon2 = poi[2 * cl + 1] * DEG2RAD;
        const float sdlat = __sinf(0.5f * (lat2 - lat1));
        const float sdlon = __sinf(0.5f * (lon2 - lon1));
        float a = sdlat * sdlat + coslat1 * __cosf(lat2) * (sdlon * sdlon);
        a = fminf(fmaxf(a, 0.0f), 1.0f);
        s_ds[k] = TWO_R * asinf(sqrtf(a));
    }

    __syncthreads();

    // --- stream the output: K*E = 25000 floats = 6250 f32x4 per (n,m)
    f32x4* __restrict__ out4 =
        reinterpret_cast<f32x4*>(out + (size_t)nm * (PK * PE));
    constexpr int NV = (PK * PE) / 4;  // 6250

    for (int t = tid; t < NV; t += 256) {
        const unsigned f = (unsigned)t * 4u;
        unsigned k = f / (unsigned)PE;        // magic-mul division by 50
        unsigned e = f - k * (unsigned)PE;
        float ds = s_ds[k];
        f32x4 v;
        v.x = fmaf(ds, s_D[e], s_C[e]);
        if (++e == PE) { e = 0; ds = s_ds[++k]; }
        v.y = fmaf(ds, s_D[e], s_C[e]);
        if (++e == PE) { e = 0; ds = s_ds[++k]; }
        v.z = fmaf(ds, s_D[e], s_C[e]);
        if (++e == PE) { e = 0; ds = s_ds[++k]; }
        v.w = fmaf(ds, s_D[e], s_C[e]);
        __builtin_nontemporal_store(v, &out4[t]);  // nt dwordx4 — fill's shape
    }
}

extern "C" void kernel_launch(void* const* d_in, const int* in_sizes, int n_in,
                              void* d_out, int out_size, void* d_ws, size_t ws_size,
                              hipStream_t stream) {
    const int*   traj_loc = (const int*)  d_in[0];
    const float* poi      = (const float*)d_in[1];
    const float* vec      = (const float*)d_in[2];
    const int*   traj_len = (const int*)  d_in[3];
    const int*   cand     = (const int*)  d_in[4];
    const float* emb_su   = (const float*)d_in[5];
    const float* emb_sl   = (const float*)d_in[6];
    const float* emb_tu   = (const float*)d_in[7];
    const float* emb_tl   = (const float*)d_in[8];
    float* out = (float*)d_out;

    dim3 grid(PN * PM);   // 3200 blocks, one per (n,m)
    dim3 block(256);
    embed_kernel<<<grid, block, 0, stream>>>(
        traj_loc, poi, vec, traj_len, cand,
        emb_su, emb_sl, emb_tu, emb_tl, out);
}